// Round 7
// baseline (783.309 us; speedup 1.0000x reference)
//
#include <hip/hip_runtime.h>

// B=64 batches, n=64 nodes/batch, H=128, epg=2048 edges/batch
// Per-batch-group mega-kernel: 64 groups x 8 blocks; group-local 8-wide barriers.
#define KK 52
#define NKOUT 3328
#define NEG 0.01f
#define BPG 8

typedef __attribute__((ext_vector_type(8))) __bf16 bf16x8;
typedef __attribute__((ext_vector_type(16))) float floatx16;

__device__ __forceinline__ float lrelu(float v){ return v > 0.f ? v : NEG*v; }

// LDS layout for MFMA chunks: row pitch 40 bf16 (80B); XOR swizzle on 16B chunks
#define SW(r, ko) ((r)*40 + ((ko) ^ ((((r)>>3)&3) << 3)))

__device__ __forceinline__ void split_store8(const float* vv, __bf16* P0, __bf16* P1, __bf16* P2, int addr){
  bf16x8 p1, p2, p3;
  #pragma unroll
  for (int j = 0; j < 8; j++){
    __bf16 b1 = (__bf16)vv[j];
    float r1 = vv[j] - (float)b1;
    __bf16 b2 = (__bf16)r1;
    float r2 = r1 - (float)b2;
    p1[j] = b1; p2[j] = b2; p3[j] = (__bf16)r2;
  }
  *(bf16x8*)(P0 + addr) = p1;
  *(bf16x8*)(P1 + addr) = p2;
  *(bf16x8*)(P2 + addr) = p3;
}

__device__ __forceinline__ void split8r(const float* vv, bf16x8* q1, bf16x8* q2, bf16x8* q3){
  bf16x8 p1, p2, p3;
  #pragma unroll
  for (int j = 0; j < 8; j++){
    __bf16 b1 = (__bf16)vv[j];
    float r1 = vv[j] - (float)b1;
    __bf16 b2 = (__bf16)r1;
    float r2 = r1 - (float)b2;
    p1[j] = b1; p2[j] = b2; p3[j] = (__bf16)r2;
  }
  *q1 = p1; *q2 = p2; *q3 = p3;
}

__device__ __forceinline__ void mfma6(const __bf16* A0, const __bf16* A1, const __bf16* A2,
                                      const __bf16* B0, const __bf16* B1, const __bf16* B2,
                                      int aoff, int boff, floatx16* acc){
  bf16x8 a1 = *(const bf16x8*)(A0 + aoff);
  bf16x8 a2 = *(const bf16x8*)(A1 + aoff);
  bf16x8 a3 = *(const bf16x8*)(A2 + aoff);
  bf16x8 b1 = *(const bf16x8*)(B0 + boff);
  bf16x8 b2 = *(const bf16x8*)(B1 + boff);
  bf16x8 b3 = *(const bf16x8*)(B2 + boff);
  floatx16 c = *acc;
  c = __builtin_amdgcn_mfma_f32_32x32x16_bf16(a1,b1,c,0,0,0);
  c = __builtin_amdgcn_mfma_f32_32x32x16_bf16(a1,b2,c,0,0,0);
  c = __builtin_amdgcn_mfma_f32_32x32x16_bf16(a2,b1,c,0,0,0);
  c = __builtin_amdgcn_mfma_f32_32x32x16_bf16(a1,b3,c,0,0,0);
  c = __builtin_amdgcn_mfma_f32_32x32x16_bf16(a3,b1,c,0,0,0);
  c = __builtin_amdgcn_mfma_f32_32x32x16_bf16(a2,b2,c,0,0,0);
  *acc = c;
}

__device__ __forceinline__ void mfma6r(bf16x8 a1, bf16x8 a2, bf16x8 a3,
                                       bf16x8 b1, bf16x8 b2, bf16x8 b3, floatx16* acc){
  floatx16 c = *acc;
  c = __builtin_amdgcn_mfma_f32_32x32x16_bf16(a1,b1,c,0,0,0);
  c = __builtin_amdgcn_mfma_f32_32x32x16_bf16(a1,b2,c,0,0,0);
  c = __builtin_amdgcn_mfma_f32_32x32x16_bf16(a2,b1,c,0,0,0);
  c = __builtin_amdgcn_mfma_f32_32x32x16_bf16(a1,b3,c,0,0,0);
  c = __builtin_amdgcn_mfma_f32_32x32x16_bf16(a3,b1,c,0,0,0);
  c = __builtin_amdgcn_mfma_f32_32x32x16_bf16(a2,b2,c,0,0,0);
  *acc = c;
}

// ---- group-local barrier: 8 blocks of one batch; monotone stage values ----
// Arrival: relaxed agent store to own 128B-spaced slot. Poll own group's 8 slots.
// No leader, no release flags, no cross-group coupling -> no convergence tail.
__device__ __forceinline__ void bsync(int* slots, int g, int j, int stage){
  __threadfence();
  __syncthreads();
  if (threadIdx.x == 0){
    __hip_atomic_store(&slots[(g*BPG + j)*32], stage, __ATOMIC_RELAXED, __HIP_MEMORY_SCOPE_AGENT);
    int base = g*BPG*32;
    for (;;){
      int ok = 1;
      #pragma unroll
      for (int i = 0; i < BPG; i++)
        ok &= (__hip_atomic_load(&slots[base + i*32], __ATOMIC_RELAXED, __HIP_MEMORY_SCOPE_AGENT) >= stage);
      if (ok) break;
      __builtin_amdgcn_s_sleep(2);
    }
  }
  __syncthreads();
  __threadfence();
}

// ---- generic 64x128 MFMA GEMM core (bf16x6 fp32-faithful), fp32 A and B on-the-fly split ----
__device__ __forceinline__ void g_gemm(const float* A0, int ldA,
                                       const float* __restrict__ W0, int ldW, int K,
                                       __bf16* pb, floatx16* oA, floatx16* oB){
  __bf16 *As0 = pb, *As1 = pb+2560, *As2 = pb+5120;
  __bf16 *Bs0 = pb+7680, *Bs1 = pb+12800, *Bs2 = pb+17920;
  int tid = threadIdx.x;
  int sar = tid >> 2, sako = (tid & 3)*8;
  int bn = tid & 127, bk = (tid >> 7)*16;
  int wv_ = tid >> 6, L = tid & 63, m = L & 31, half = L >> 5;
  int rA = 32*(wv_ & 1) + m, rB0 = (wv_ >> 1)*32 + m, rB1 = rB0 + 64;
  const float* arow = A0 + (size_t)sar*ldA;
  floatx16 accA, accB;
  #pragma unroll
  for (int i = 0; i < 16; i++){ accA[i] = 0.f; accB[i] = 0.f; }
  float ra[8], wv[16];
  {
    float4 v0 = *(const float4*)(arow + sako);
    float4 v1 = *(const float4*)(arow + sako + 4);
    ra[0]=v0.x; ra[1]=v0.y; ra[2]=v0.z; ra[3]=v0.w; ra[4]=v1.x; ra[5]=v1.y; ra[6]=v1.z; ra[7]=v1.w;
    #pragma unroll
    for (int j = 0; j < 16; j++) wv[j] = W0[(size_t)(bk + j)*ldW + bn];
  }
  for (int k0 = 0; k0 < K; k0 += 32){
    split_store8(ra, As0, As1, As2, SW(sar, sako));
    split_store8(wv,     Bs0, Bs1, Bs2, SW(bn, bk));
    split_store8(wv + 8, Bs0, Bs1, Bs2, SW(bn, bk + 8));
    __syncthreads();
    int k1 = k0 + 32;
    float ra2[8], wv2[16];
    if (k1 < K){
      float4 v0 = *(const float4*)(arow + k1 + sako);
      float4 v1 = *(const float4*)(arow + k1 + sako + 4);
      ra2[0]=v0.x; ra2[1]=v0.y; ra2[2]=v0.z; ra2[3]=v0.w; ra2[4]=v1.x; ra2[5]=v1.y; ra2[6]=v1.z; ra2[7]=v1.w;
      #pragma unroll
      for (int j = 0; j < 16; j++) wv2[j] = W0[(size_t)(k1 + bk + j)*ldW + bn];
    }
    #pragma unroll
    for (int kg = 0; kg < 2; kg++){
      int ko = kg*16 + half*8;
      mfma6(As0,As1,As2, Bs0,Bs1,Bs2, SW(rA,ko), SW(rB0,ko), &accA);
      mfma6(As0,As1,As2, Bs0,Bs1,Bs2, SW(rA,ko), SW(rB1,ko), &accB);
    }
    __syncthreads();
    if (k1 < K){
      #pragma unroll
      for (int j = 0; j < 8; j++) ra[j] = ra2[j];
      #pragma unroll
      for (int j = 0; j < 16; j++) wv[j] = wv2[j];
    }
  }
  *oA = accA; *oB = accB;
}

// ---- generic 64x64-tile MFMA GEMM core (fp32 A + fp32 B, on-the-fly split) ----
__device__ __forceinline__ void g_gemm64(const float* __restrict__ A0, int ldA,
                                         const float* __restrict__ W0, int ldW, int K,
                                         __bf16* pb, floatx16* oC){
  __bf16 *As0 = pb, *As1 = pb+2560, *As2 = pb+5120;
  __bf16 *Bs0 = pb+7680, *Bs1 = pb+10240, *Bs2 = pb+12800;
  int tid = threadIdx.x;
  int sar = tid >> 2, sako = (tid & 3)*8;
  int bn = tid & 63, bk = (tid >> 6)*8;
  int wv_ = tid >> 6, L = tid & 63, m = L & 31, half = L >> 5;
  int rA = 32*(wv_ & 1) + m, rB = 32*(wv_ >> 1) + m;
  const float* arow = A0 + (size_t)sar*ldA;
  floatx16 acc;
  #pragma unroll
  for (int i = 0; i < 16; i++) acc[i] = 0.f;
  float ra[8], wv[8];
  {
    float4 v0 = *(const float4*)(arow + sako);
    float4 v1 = *(const float4*)(arow + sako + 4);
    ra[0]=v0.x; ra[1]=v0.y; ra[2]=v0.z; ra[3]=v0.w; ra[4]=v1.x; ra[5]=v1.y; ra[6]=v1.z; ra[7]=v1.w;
    #pragma unroll
    for (int j = 0; j < 8; j++) wv[j] = W0[(size_t)(bk + j)*ldW + bn];
  }
  for (int k0 = 0; k0 < K; k0 += 32){
    split_store8(ra, As0, As1, As2, SW(sar, sako));
    split_store8(wv, Bs0, Bs1, Bs2, SW(bn, bk));
    __syncthreads();
    int k1 = k0 + 32;
    float ra2[8], wv2[8];
    if (k1 < K){
      float4 v0 = *(const float4*)(arow + k1 + sako);
      float4 v1 = *(const float4*)(arow + k1 + sako + 4);
      ra2[0]=v0.x; ra2[1]=v0.y; ra2[2]=v0.z; ra2[3]=v0.w; ra2[4]=v1.x; ra2[5]=v1.y; ra2[6]=v1.z; ra2[7]=v1.w;
      #pragma unroll
      for (int j = 0; j < 8; j++) wv2[j] = W0[(size_t)(k1 + bk + j)*ldW + bn];
    }
    #pragma unroll
    for (int kg = 0; kg < 2; kg++){
      int ko = kg*16 + half*8;
      mfma6(As0,As1,As2, Bs0,Bs1,Bs2, SW(rA,ko), SW(rB,ko), &acc);
    }
    __syncthreads();
    if (k1 < K){
      #pragma unroll
      for (int j = 0; j < 8; j++){ ra[j] = ra2[j]; wv[j] = wv2[j]; }
    }
  }
  *oC = acc;
}

// ---- 64x64-tile W1 GEMM (K=384): h=[a,q,a*q] synthesized; W1 FOLD on-the-fly (fp32, identical
//      values to the old prefold); a = arow (+ arow2 fp32 partial sum, R6-validated) ----
__device__ __forceinline__ void g_gemm_h64f(const float* arow, const float* arow2,
                                            const float* __restrict__ qrow,
                                            const float* __restrict__ W1z, int colbase,
                                            __bf16* pb, floatx16* oC){
  __bf16 *As0 = pb, *As1 = pb+2560, *As2 = pb+5120;
  __bf16 *Bs0 = pb+7680, *Bs1 = pb+10240, *Bs2 = pb+12800;
  int tid = threadIdx.x;
  int sar = tid >> 2, sako = (tid & 3)*8;
  int bn = tid & 63, bk = (tid >> 6)*8;
  int col = colbase + bn;
  int wv_ = tid >> 6, L = tid & 63, m = L & 31, half = L >> 5;
  int rA = 32*(wv_ & 1) + m, rB = 32*(wv_ >> 1) + m;
  auto loadAv = [&](int kl, float* r){
    float4 a0 = *(const float4*)(arow + kl), a1 = *(const float4*)(arow + kl + 4);
    if (arow2){
      float4 c0 = *(const float4*)(arow2 + kl), c1 = *(const float4*)(arow2 + kl + 4);
      a0 = make_float4(a0.x + c0.x, a0.y + c0.y, a0.z + c0.z, a0.w + c0.w);
      a1 = make_float4(a1.x + c1.x, a1.y + c1.y, a1.z + c1.z, a1.w + c1.w);
    }
    r[0]=a0.x; r[1]=a0.y; r[2]=a0.z; r[3]=a0.w; r[4]=a1.x; r[5]=a1.y; r[6]=a1.z; r[7]=a1.w;
  };
  auto loadA = [&](int k0, float* r){
    int seg = k0 >> 7, kl = (k0 & 127) + sako;
    if (seg == 0){
      loadAv(kl, r);
    } else if (seg == 1){
      float4 q0 = *(const float4*)(qrow + kl), q1 = *(const float4*)(qrow + kl + 4);
      r[0]=q0.x; r[1]=q0.y; r[2]=q0.z; r[3]=q0.w; r[4]=q1.x; r[5]=q1.y; r[6]=q1.z; r[7]=q1.w;
    } else {
      float av[8];
      loadAv(kl, av);
      float4 q0 = *(const float4*)(qrow + kl), q1 = *(const float4*)(qrow + kl + 4);
      r[0]=av[0]*q0.x; r[1]=av[1]*q0.y; r[2]=av[2]*q0.z; r[3]=av[3]*q0.w;
      r[4]=av[4]*q1.x; r[5]=av[5]*q1.y; r[6]=av[6]*q1.z; r[7]=av[7]*q1.w;
    }
  };
  auto loadB = [&](int k0, float* r){
    #pragma unroll
    for (int t = 0; t < 8; t++){
      int kr = k0 + bk + t;
      float v;
      if (kr < 128)       v = W1z[kr*256 + col] + W1z[(kr + 256)*256 + col];
      else if (kr < 256)  v = W1z[kr*256 + col] - W1z[(kr + 128)*256 + col];
      else                v = W1z[(kr + 128)*256 + col];
      r[t] = v;
    }
  };
  floatx16 acc;
  #pragma unroll
  for (int i = 0; i < 16; i++) acc[i] = 0.f;
  float ra[8], wv[8];
  loadA(0, ra); loadB(0, wv);
  for (int k0 = 0; k0 < 384; k0 += 32){
    split_store8(ra, As0, As1, As2, SW(sar, sako));
    split_store8(wv, Bs0, Bs1, Bs2, SW(bn, bk));
    __syncthreads();
    int k1 = k0 + 32;
    float ra2[8], wv2[8];
    if (k1 < 384){ loadA(k1, ra2); loadB(k1, wv2); }
    #pragma unroll
    for (int kg = 0; kg < 2; kg++){
      int ko = kg*16 + half*8;
      mfma6(As0,As1,As2, Bs0,Bs1,Bs2, SW(rA,ko), SW(rB,ko), &acc);
    }
    __syncthreads();
    if (k1 < 384){
      #pragma unroll
      for (int j = 0; j < 8; j++){ ra[j] = ra2[j]; wv[j] = wv2[j]; }
    }
  }
  *oC = acc;
}

__device__ __forceinline__ void c_write(floatx16 accA, floatx16 accB, float* C0, int ldC, int act){
  int tid = threadIdx.x, wv_ = tid >> 6, L = tid & 63, m = L & 31, half = L >> 5;
  int rB0 = (wv_ >> 1)*32 + m, rB1 = rB0 + 64;
  int row0 = 32*(wv_ & 1) + 4*half;
  #pragma unroll
  for (int reg = 0; reg < 16; reg++){
    int row = row0 + (reg & 3) + 8*(reg >> 2);
    float va = accA[reg], vb = accB[reg];
    if (act){ va = lrelu(va); vb = lrelu(vb); }
    C0[(size_t)row*ldC + rB0] = va;
    C0[(size_t)row*ldC + rB1] = vb;
  }
}

__device__ __forceinline__ void c_write64(floatx16 acc, float* C0, int ldC, int act){
  int tid = threadIdx.x, wv_ = tid >> 6, L = tid & 63, m = L & 31, half = L >> 5;
  int col = 32*(wv_ >> 1) + m;
  int row0 = 32*(wv_ & 1) + 4*half;
  #pragma unroll
  for (int reg = 0; reg < 16; reg++){
    int row = row0 + (reg & 3) + 8*(reg >> 2);
    float v = acc[reg];
    if (act) v = lrelu(v);
    C0[(size_t)row*ldC + col] = v;
  }
}

// ---- double hop (A^T twice), A in LDS; src either global rows (ld128) or LDS (ldV); dst ld128 ----
__device__ __forceinline__ void hop2_run(const float* A, const float* VfullL, int ldV,
                                         const float* srcG, float* dstG, int dstOff,
                                         float* Vt, float* Tt, int fbeg, int fend){
  int tid = threadIdx.x;
  int tc = (tid & 31)*2, tf = (tid >> 5)*4;
  for (int f0 = fbeg; f0 < fend; f0 += 32){
    if (!VfullL){
      for (int o = tid; o < 2048; o += 256){
        int r = o >> 5, f = o & 31;
        Vt[o] = srcG[r*128 + f0 + f];
      }
      __syncthreads();
    }
    float a00,a01,a02,a03,a10,a11,a12,a13;
    a00=a01=a02=a03=a10=a11=a12=a13=0.f;
    for (int r = 0; r < 64; r++){
      float x0 = A[r*64 + tc], x1 = A[r*64 + tc + 1];
      float4 v4 = VfullL ? *(const float4*)&VfullL[r*ldV + f0 + tf]
                         : *(const float4*)&Vt[r*32 + tf];
      a00 += x0*v4.x; a01 += x0*v4.y; a02 += x0*v4.z; a03 += x0*v4.w;
      a10 += x1*v4.x; a11 += x1*v4.y; a12 += x1*v4.z; a13 += x1*v4.w;
    }
    *(float4*)&Tt[tc*32 + tf]     = make_float4(a00,a01,a02,a03);
    *(float4*)&Tt[(tc+1)*32 + tf] = make_float4(a10,a11,a12,a13);
    __syncthreads();
    a00=a01=a02=a03=a10=a11=a12=a13=0.f;
    for (int r = 0; r < 64; r++){
      float x0 = A[r*64 + tc], x1 = A[r*64 + tc + 1];
      float4 v4 = *(const float4*)&Tt[r*32 + tf];
      a00 += x0*v4.x; a01 += x0*v4.y; a02 += x0*v4.z; a03 += x0*v4.w;
      a10 += x1*v4.x; a11 += x1*v4.y; a12 += x1*v4.z; a13 += x1*v4.w;
    }
    *(float4*)(dstG + tc*128 + dstOff + f0 + tf)     = make_float4(a00,a01,a02,a03);
    *(float4*)(dstG + (tc+1)*128 + dstOff + f0 + tf) = make_float4(a10,a11,a12,a13);
    __syncthreads();
  }
}

// ===== S1 job: build Ew/deg + hop2 half (j<2) =====
__device__ void build_job(int b, int fh, float* pf,
                          const int* __restrict__ ei, const float* __restrict__ ew,
                          const float* __restrict__ x, float* A_g, float* M_g, float* xq){
  int tid = threadIdx.x;
  float* Ws = pf; float* Mc = pf + 4096; float* dv = pf + 8192;
  for (int i = tid; i < 4096; i += 256){ Ws[i] = 0.f; Mc[i] = 0.f; }
  __syncthreads();
  const int* r0 = ei + b*2048;
  const int* c0 = ei + 64*2048 + b*2048;
  const float* w0 = ew + b*2048;
  int base = b*64;
  for (int e = tid; e < 2048; e += 256){
    int r = r0[e] - base, c = c0[e] - base;
    atomicAdd(&Ws[r*64 + c], w0[e]);
    atomicAdd(&Mc[r*64 + c], 1.f);
  }
  if (tid < 64){ atomicAdd(&Ws[tid*65], 1.f); atomicAdd(&Mc[tid*65], 1.f); }
  __syncthreads();
  if (tid < 64){
    float d = 0.f;
    for (int r = 0; r < 64; r++) d += Ws[r*64 + tid];
    dv[tid] = d > 0.f ? rsqrtf(fmaxf(d, 1e-12f)) : 0.f;
  }
  __syncthreads();
  for (int i = tid; i < 4096; i += 256){
    int r = i >> 6, c = i & 63;
    float a = dv[r]*Ws[i]*dv[c];
    Ws[i] = a;
    if (fh == 0){
      A_g[b*4096 + i] = a;
      M_g[b*4096 + i] = Mc[i];
    }
  }
  __syncthreads();
  hop2_run(Ws, nullptr, 0, x + (size_t)b*8192, xq + (size_t)b*8192, 0, pf + 8256, pf + 10304,
           fh*64, fh*64 + 64);
}

// ===== S3/S6 job: W2 partial-logit GEMM =====
__device__ void w2p_job(int b, int z, int nh, int head0, float* pf, __bf16* pb,
                        const float* __restrict__ h1, const float* __restrict__ W2,
                        const float* __restrict__ W3, float* __restrict__ lp){
  float* lgp = pf + 7808;
  int tid = threadIdx.x;
  floatx16 c;
  g_gemm64(h1 + (size_t)z*1048576 + (size_t)b*16384, 256,
           W2 + (size_t)(head0 + z)*32768 + nh*64, 128, 256, pb, &c);
  int wv_ = tid >> 6, L = tid & 63, m = L & 31, half = L >> 5;
  int col = 32*(wv_ >> 1) + m;
  float w = W3[(head0 + z)*128 + nh*64 + col];
  float v[16];
  #pragma unroll
  for (int reg = 0; reg < 16; reg++) v[reg] = lrelu(c[reg])*w;
  #pragma unroll
  for (int off = 1; off < 32; off <<= 1)
    #pragma unroll
    for (int reg = 0; reg < 16; reg++) v[reg] += __shfl_xor(v[reg], off);
  if (m == 0){
    #pragma unroll
    for (int reg = 0; reg < 16; reg++) lgp[wv_*32 + half*16 + reg] = v[reg];
  }
  __syncthreads();
  if (tid < 64){
    int row = tid, rh = row >> 5, rem = row & 31;
    int hf = (rem >> 2) & 1, rg = (rem & 3) + 4*(rem >> 3);
    float p = lgp[rh*32 + hf*16 + rg] + lgp[(rh + 2)*32 + hf*16 + rg];
    lp[(z*2 + nh)*4096 + b*64 + row] = p;
  }
}

// ===== S4 job: edge softmax + S + y=Ew^T xl + x_c + wkg-partial GEMM + hop2 (LDS-aliased) =====
__device__ void edgehop_job(int b, int fh, float* pf,
                            const float* __restrict__ M_g, const float* __restrict__ lp,
                            const float* __restrict__ x, const float* __restrict__ xl0g,
                            const float* __restrict__ xl1g, const float* __restrict__ A_g,
                            const float* __restrict__ Wk,
                            float* S_g, float* ap, float* xq2){
  float* Mc   = pf;           // 4096; later reused for Ab
  float* xh   = pf + 4096;    // 4096
  float* xl0h = pf + 8192;    // 4096; later reused for Tt
  float* xl1h = pf + 12288;   // 4096
  float* f1s  = pf + 16384;   // 64
  float* f2s  = pf + 16448;   // 64
  int tid = threadIdx.x;
  int foff = fh*64;
  for (int i = tid; i < 4096; i += 256) Mc[i] = M_g[b*4096 + i];
  for (int o = tid*4; o < 4096; o += 1024){
    int r = o >> 6, f = o & 63;
    *(float4*)&xh[o]   = *(const float4*)(x    + (size_t)b*8192 + r*128 + foff + f);
    *(float4*)&xl0h[o] = *(const float4*)(xl0g + (size_t)b*8192 + r*128 + foff + f);
    *(float4*)&xl1h[o] = *(const float4*)(xl1g + (size_t)b*8192 + r*128 + foff + f);
  }
  if (tid < 128){
    int z = tid >> 6, r = tid & 63;
    float d = lp[(z*2)*4096 + b*64 + r] + lp[(z*2 + 1)*4096 + b*64 + r];
    float l = lrelu(d);
    float mx = l;
    #pragma unroll
    for (int off = 32; off; off >>= 1) mx = fmaxf(mx, __shfl_xor(mx, off));
    float e = expf(l - mx);
    float s = e;
    #pragma unroll
    for (int off = 32; off; off >>= 1) s += __shfl_xor(s, off);
    (z ? f2s : f1s)[r] = e/s;
  }
  __syncthreads();
  {
    int c = tid >> 2, sub = tid & 3;
    float m = -1e30f;
    for (int r = sub; r < 64; r += 4)
      if (Mc[r*64 + c] > 0.f) m = fmaxf(m, lrelu(f1s[c] + f2s[r]));
    m = fmaxf(m, __shfl_xor(m, 1));
    m = fmaxf(m, __shfl_xor(m, 2));
    float s = 0.f;
    for (int r = sub; r < 64; r += 4){
      float mc = Mc[r*64 + c];
      if (mc > 0.f) s += mc*expf(lrelu(f1s[c] + f2s[r]) - m);
    }
    s += __shfl_xor(s, 1);
    s += __shfl_xor(s, 2);
    for (int r = sub; r < 64; r += 4){
      float mc = Mc[r*64 + c];
      float v = 0.f;
      if (mc > 0.f) v = mc*expf(lrelu(f1s[c] + f2s[r]) - m)/s;
      Mc[r*64 + c] = v;
    }
  }
  __syncthreads();
  if (fh == 0)
    for (int i = tid; i < 4096; i += 256) S_g[b*4096 + i] = Mc[i];
  {
    int tc = (tid & 15)*4, tf = (tid >> 4)*4;
    float a0[4][4], a1[4][4];
    #pragma unroll
    for (int i = 0; i < 4; i++)
      #pragma unroll
      for (int j = 0; j < 4; j++){ a0[i][j] = 0.f; a1[i][j] = 0.f; }
    for (int r = 0; r < 64; r++){
      float4 e4 = *(const float4*)&Mc[r*64 + tc];
      float4 p0 = *(const float4*)&xl0h[r*64 + tf];
      float4 p1 = *(const float4*)&xl1h[r*64 + tf];
      float e_[4] = {e4.x,e4.y,e4.z,e4.w};
      float p0_[4] = {p0.x,p0.y,p0.z,p0.w};
      float p1_[4] = {p1.x,p1.y,p1.z,p1.w};
      #pragma unroll
      for (int ci = 0; ci < 4; ci++)
        #pragma unroll
        for (int fj = 0; fj < 4; fj++){
          a0[ci][fj] += e_[ci]*p0_[fj];
          a1[ci][fj] += e_[ci]*p1_[fj];
        }
    }
    __syncthreads();
    #pragma unroll
    for (int ci = 0; ci < 4; ci++){
      int c = tc + ci;
      float4 xv = *(const float4*)&xh[c*64 + tf];
      float4 o;
      o.x = 0.5f*(lrelu(xv.x + a0[ci][0]) + lrelu(xv.x + a1[ci][0]));
      o.y = 0.5f*(lrelu(xv.y + a0[ci][1]) + lrelu(xv.y + a1[ci][1]));
      o.z = 0.5f*(lrelu(xv.z + a0[ci][2]) + lrelu(xv.z + a1[ci][2]));
      o.w = 0.5f*(lrelu(xv.w + a0[ci][3]) + lrelu(xv.w + a1[ci][3]));
      *(float4*)&xh[c*64 + tf] = o;
    }
  }
  __syncthreads();   // xh = x_c half finalized; Mc/xl0h free to overwrite
  // ---- wkg partial-K GEMM: ap[fh][z][b] = xh @ Wkg[z][K rows foff..foff+63]
  //      B split on-the-fly from Wk heads 2/3 (bit-identical to R6's presplit path) ----
  {
    int wv_ = tid >> 6, L = tid & 63, m = L & 31, half = L >> 5;
    int rA = 32*(wv_ & 1) + m, rB = 32*(wv_ >> 1) + m;
    bf16x8 af[4][3];
    #pragma unroll
    for (int kg = 0; kg < 4; kg++){
      int ko = kg*16 + half*8;
      float av[8];
      float4 v0 = *(const float4*)&xh[rA*64 + ko];
      float4 v1 = *(const float4*)&xh[rA*64 + ko + 4];
      av[0]=v0.x; av[1]=v0.y; av[2]=v0.z; av[3]=v0.w; av[4]=v1.x; av[5]=v1.y; av[6]=v1.z; av[7]=v1.w;
      split8r(av, &af[kg][0], &af[kg][1], &af[kg][2]);
    }
    int row0 = 32*(wv_ & 1) + 4*half;
    #pragma unroll
    for (int z = 0; z < 2; z++){
      const float* Wz = Wk + (size_t)(2 + z)*16384;
      #pragma unroll
      for (int nh = 0; nh < 2; nh++){
        floatx16 acc;
        #pragma unroll
        for (int i = 0; i < 16; i++) acc[i] = 0.f;
        int colB = nh*64 + rB;
        #pragma unroll
        for (int kg = 0; kg < 4; kg++){
          int ko = kg*16 + half*8;
          float bv[8];
          #pragma unroll
          for (int i = 0; i < 8; i++) bv[i] = Wz[(size_t)(foff + ko + i)*128 + colB];
          bf16x8 b1, b2, b3;
          split8r(bv, &b1, &b2, &b3);
          mfma6r(af[kg][0], af[kg][1], af[kg][2], b1, b2, b3, &acc);
        }
        float* C0 = ap + (size_t)fh*1048576 + (size_t)z*524288 + (size_t)b*8192 + nh*64;
        #pragma unroll
        for (int reg = 0; reg < 16; reg++){
          int row = row0 + (reg & 3) + 8*(reg >> 2);
          C0[(size_t)row*128 + rB] = acc[reg];
        }
      }
    }
  }
  for (int i = tid*4; i < 4096; i += 1024)
    *(float4*)&Mc[i] = *(const float4*)(A_g + b*4096 + i);   // Ab into Mc slot
  __syncthreads();
  hop2_run(Mc, xh, 64, nullptr, xq2 + (size_t)b*8192, foff, xl0h, xl0h, 0, 64);  // Tt in xl0h slot
}

// ===== S7 job: pool (softmaxes + bitonic top-52 + x_out) + A2 diagonal block =====
__device__ void A2c_job(int b, float* pf, const float* __restrict__ lp, const float* __restrict__ x,
                        const float* __restrict__ A_g, const float* __restrict__ S_g,
                        float* outA2, float* outX, float* outB, float* outP){
  float* At = pf;             // 64*68
  float* Sp = pf + 4352;      // 64*56
  float* Tq = pf + 7936;      // 64*56
  int*   pi = (int*)(pf + 11520);
  float* pv = pf + 11584;
  int tid = threadIdx.x;
  if (tid < 64){
    int lane = tid;
    float f[2];
    #pragma unroll
    for (int z = 0; z < 2; z++){
      float d = lp[(z*2)*4096 + b*64 + lane] + lp[(z*2 + 1)*4096 + b*64 + lane];
      float l = lrelu(d);
      float mx = l;
      #pragma unroll
      for (int off = 32; off; off >>= 1) mx = fmaxf(mx, __shfl_xor(mx, off));
      float e = expf(l - mx);
      float sm = e;
      #pragma unroll
      for (int off = 32; off; off >>= 1) sm += __shfl_xor(sm, off);
      f[z] = e/sm;
    }
    float l = f[0] + f[1];
    float m = l;
    #pragma unroll
    for (int off = 32; off; off >>= 1) m = fmaxf(m, __shfl_xor(m, off));
    float e = expf(l - m);
    float sm = e;
    #pragma unroll
    for (int off = 32; off; off >>= 1) sm += __shfl_xor(sm, off);
    float v = e/sm;
    int idx = lane;
    #pragma unroll
    for (int k = 2; k <= 64; k <<= 1){
      #pragma unroll
      for (int j = k >> 1; j > 0; j >>= 1){
        float ov = __shfl_xor(v, j);
        int   oi = __shfl_xor(idx, j);
        bool ascBlock = (lane & k) == 0;
        bool iAmLow   = (lane & j) == 0;
        bool otherPrec = (ov > v) || (ov == v && oi < idx);
        bool take = (ascBlock == iAmLow) ? otherPrec : !otherPrec;
        if (take){ v = ov; idx = oi; }
      }
    }
    pi[lane] = idx; pv[lane] = v;
    if (lane < KK){
      outB[b*KK + lane] = (float)b;
      outP[b*KK + lane] = (float)(b*64 + idx);
    }
  }
  __syncthreads();
  for (int o = tid*4; o < KK*128; o += 1024){
    int j = o >> 7, f = o & 127;
    float4 xv = *(const float4*)(x + ((size_t)b*64 + pi[j])*128 + f);
    float sv = pv[j];
    *(float4*)(outX + (size_t)b*KK*128 + o) = make_float4(xv.x*sv, xv.y*sv, xv.z*sv, xv.w*sv);
  }
  for (int idx = tid; idx < 4096; idx += 256){
    int i = idx >> 6, k = idx & 63;
    At[k*68 + i] = A_g[b*4096 + idx];
  }
  for (int idx = tid; idx < 4096; idx += 256){
    int k = idx >> 6, t = idx & 63;
    if (t < 56) Sp[k*56 + t] = (t < KK) ? S_g[b*4096 + k*64 + pi[t]] : 0.f;
  }
  __syncthreads();
  if (tid < 224){
    int i0 = (tid/14)*4, t0 = (tid % 14)*4;
    float acc[4][4];
    #pragma unroll
    for (int a = 0; a < 4; a++)
      #pragma unroll
      for (int c = 0; c < 4; c++) acc[a][c] = 0.f;
    for (int k = 0; k < 64; k++){
      float4 a4 = *(const float4*)&At[k*68 + i0];
      float4 s4 = *(const float4*)&Sp[k*56 + t0];
      float a_[4] = {a4.x,a4.y,a4.z,a4.w};
      float s_[4] = {s4.x,s4.y,s4.z,s4.w};
      #pragma unroll
      for (int ii = 0; ii < 4; ii++)
        #pragma unroll
        for (int tt = 0; tt < 4; tt++) acc[ii][tt] += a_[ii]*s_[tt];
    }
    #pragma unroll
    for (int ii = 0; ii < 4; ii++)
      *(float4*)&Tq[(i0+ii)*56 + t0] = make_float4(acc[ii][0],acc[ii][1],acc[ii][2],acc[ii][3]);
  }
  __syncthreads();
  if (tid < 169){
    int a0 = (tid/13)*4, t0 = (tid % 13)*4;
    float acc[4][4];
    #pragma unroll
    for (int a = 0; a < 4; a++)
      #pragma unroll
      for (int c = 0; c < 4; c++) acc[a][c] = 0.f;
    for (int i = 0; i < 64; i++){
      float4 s4 = *(const float4*)&Sp[i*56 + a0];
      float4 t4 = *(const float4*)&Tq[i*56 + t0];
      float s_[4] = {s4.x,s4.y,s4.z,s4.w};
      float t_[4] = {t4.x,t4.y,t4.z,t4.w};
      #pragma unroll
      for (int aa = 0; aa < 4; aa++)
        #pragma unroll
        for (int tt = 0; tt < 4; tt++) acc[aa][tt] += s_[aa]*t_[tt];
    }
    #pragma unroll
    for (int aa = 0; aa < 4; aa++){
      int a = a0 + aa;
      float4 o;
      o.x = (a == t0    ) ? 1.f : acc[aa][0];
      o.y = (a == t0 + 1) ? 1.f : acc[aa][1];
      o.z = (a == t0 + 2) ? 1.f : acc[aa][2];
      o.w = (a == t0 + 3) ? 1.f : acc[aa][3];
      *(float4*)(outA2 + (size_t)(b*KK + a)*NKOUT + b*KK + t0) = o;
    }
  }
}

// ===== per-batch-group mega-kernel: 64 groups x 8 blocks, group-local barriers =====
__global__ __launch_bounds__(256, 2) void k_all(const int* __restrict__ ei, const float* __restrict__ ew,
                                                const float* __restrict__ x, const float* __restrict__ tgt,
                                                const float* __restrict__ Wk, const float* __restrict__ W1,
                                                const float* __restrict__ W2, const float* __restrict__ W3,
                                                const float* __restrict__ linW,
                                                float* A_g, float* M_g, float* S_g, float* xq, float* xq2,
                                                float* xl0, float* xl1, float* a_buf, float* h1,
                                                float* lp, float* ap,
                                                float* outA2, float* outX, float* outB, float* outP,
                                                int* slots){
  __shared__ __align__(16) char POOL[66048];
  float* pf = (float*)POOL;
  __bf16* pb = (__bf16*)POOL;
  int blk = blockIdx.x, tid = threadIdx.x;
  int g = blk >> 3, j = blk & 7, b = g;

  // ---- S1: build+hop2 (j0,j1) | a_buf GEMM (j2,j3) | xl GEMM (j4,j5) | A2 zero rows (j6,j7) ----
  if (j < 2){
    build_job(b, j, pf, ei, ew, x, A_g, M_g, xq);
  } else if (j < 4){
    int z = j - 2;
    floatx16 cA, cB;
    g_gemm(x + (size_t)b*8192, 128, Wk + (size_t)z*16384, 128, 128, pb, &cA, &cB);
    c_write(cA, cB, a_buf + (size_t)z*524288 + (size_t)b*8192, 128, 0);
  } else if (j < 6){
    int z = j - 4;
    floatx16 cA, cB;
    g_gemm(x + (size_t)b*8192, 128, linW + (size_t)z*16384, 128, 128, pb, &cA, &cB);
    c_write(cA, cB, (z ? xl1 : xl0) + (size_t)b*8192, 128, 0);
  } else {
    // zero A2 rows [b*52 + (j-6)*26, +26) x 3328 cols (batch-local slice of output)
    float4* p = (float4*)(outA2 + (size_t)(b*52 + (j - 6)*26)*NKOUT);
    for (int i = tid; i < 26*NKOUT/4; i += 256) p[i] = make_float4(0.f,0.f,0.f,0.f);
  }
  bsync(slots, g, j, 1);

  // ---- S2: h1 pair f (8 jobs: z=j>>2, nq=j&3) ----
  {
    int z = j >> 2, nq = j & 3;
    int sar = tid >> 2;
    const float* arow = a_buf + (size_t)z*524288 + ((size_t)b*64 + sar)*128;
    const float* qrow = z ? (tgt + (size_t)b*128) : (xq + ((size_t)b*64 + sar)*128);
    floatx16 c;
    g_gemm_h64f(arow, nullptr, qrow, W1 + (size_t)z*131072, nq*64, pb, &c);
    c_write64(c, h1 + (size_t)z*1048576 + (size_t)b*16384 + nq*64, 256, 1);
  }
  bsync(slots, g, j, 2);

  // ---- S3: w2p pair f (4 jobs) ----
  if (j < 4) w2p_job(b, j >> 1, j & 1, 0, pf, pb, h1, W2, W3, lp);
  bsync(slots, g, j, 3);

  // ---- S4: edgehop + wkg-partial (2 jobs: fh=j) ----
  if (j < 2) edgehop_job(b, j, pf, M_g, lp, x, xl0, xl1, A_g, Wk, S_g, ap, xq2);
  bsync(slots, g, j, 4);

  // ---- S5: h1 pair g (8 jobs; A = ap[0]+ap[1] fp32 partial sum) ----
  {
    int z = j >> 2, nq = j & 3;
    int sar = tid >> 2;
    size_t aoff = (size_t)z*524288 + ((size_t)b*64 + sar)*128;
    const float* qrow = z ? (tgt + (size_t)b*128) : (xq2 + ((size_t)b*64 + sar)*128);
    floatx16 c;
    g_gemm_h64f(ap + aoff, ap + 1048576 + aoff, qrow, W1 + (size_t)(2 + z)*131072, nq*64, pb, &c);
    c_write64(c, h1 + (size_t)z*1048576 + (size_t)b*16384 + nq*64, 256, 1);
  }
  bsync(slots, g, j, 5);

  // ---- S6: w2p pair g (4 jobs) ----
  if (j < 4) w2p_job(b, j >> 1, j & 1, 2, pf, pb, h1, W2, W3, lp);
  bsync(slots, g, j, 6);

  // ---- S7: pool + A2 diagonal block (1 job) ----
  if (j == 0) A2c_job(b, pf, lp, x, A_g, S_g, outA2, outX, outB, outP);
}

extern "C" void kernel_launch(void* const* d_in, const int* in_sizes, int n_in,
                              void* d_out, int out_size, void* d_ws, size_t ws_size,
                              hipStream_t stream){
  const float* x    = (const float*)d_in[0];
  const int*   ei   = (const int*)d_in[1];
  const float* ew   = (const float*)d_in[2];
  const float* tgt  = (const float*)d_in[3];
  const float* Wk   = (const float*)d_in[5];
  const float* W1   = (const float*)d_in[6];
  const float* W2   = (const float*)d_in[7];
  const float* W3   = (const float*)d_in[8];
  const float* linW = (const float*)d_in[9];
  float* out = (float*)d_out;

  float* wf   = (float*)d_ws;
  float* A_g  = wf;
  float* M_g  = wf + 262144;
  float* S_g  = wf + 524288;
  float* xq   = wf + 786432;
  float* xq2  = wf + 1310720;
  float* xl0  = wf + 1835008;
  float* xl1  = wf + 2359296;
  float* a_buf= wf + 2883584;              // 2 x 524288 (pair f)
  float* h1   = wf + 3932160;              // 2 x 1048576 fp32
  float* lp   = wf + 6029312;              // 4 x 4096 partial logits
  float* ap   = wf + 6045696;              // [fh 2][z 2][b 64][64 x 128] fp32
  int*  slots = (int*)(wf + 8142848);      // 512 slots x 128B = 64 KB

  float* outX  = out;
  float* outA2 = out + 425984;
  float* outB  = out + 425984 + 11075584;
  float* outP  = outB + NKOUT;

  hipMemsetAsync(slots, 0, 65536, stream);
  k_all<<<dim3(512), dim3(256), 0, stream>>>(ei, ew, x, tgt, Wk, W1, W2, W3, linW,
                                             A_g, M_g, S_g, xq, xq2, xl0, xl1, a_buf, h1,
                                             lp, ap, outA2, outX, outB, outP, slots);
}

// Round 8
// 214.902 us; speedup vs baseline: 3.6450x; 3.6450x over previous
//
#include <hip/hip_runtime.h>

// B=64 batches, n=64 nodes/batch, H=128, epg=2048 edges/batch
#define KK 52
#define NKOUT 3328
#define NEG 0.01f

typedef __attribute__((ext_vector_type(8))) __bf16 bf16x8;
typedef __attribute__((ext_vector_type(16))) float floatx16;

__device__ __forceinline__ float lrelu(float v){ return v > 0.f ? v : NEG*v; }

// LDS layout for MFMA chunks: row pitch 40 bf16 (80B); XOR swizzle on 16B chunks
#define SW(r, ko) ((r)*40 + ((ko) ^ ((((r)>>3)&3) << 3)))

__device__ __forceinline__ void split_store8(const float* vv, __bf16* P0, __bf16* P1, __bf16* P2, int addr){
  bf16x8 p1, p2, p3;
  #pragma unroll
  for (int j = 0; j < 8; j++){
    __bf16 b1 = (__bf16)vv[j];
    float r1 = vv[j] - (float)b1;
    __bf16 b2 = (__bf16)r1;
    float r2 = r1 - (float)b2;
    p1[j] = b1; p2[j] = b2; p3[j] = (__bf16)r2;
  }
  *(bf16x8*)(P0 + addr) = p1;
  *(bf16x8*)(P1 + addr) = p2;
  *(bf16x8*)(P2 + addr) = p3;
}

__device__ __forceinline__ void mfma6(const __bf16* A0, const __bf16* A1, const __bf16* A2,
                                      const __bf16* B0, const __bf16* B1, const __bf16* B2,
                                      int aoff, int boff, floatx16* acc){
  bf16x8 a1 = *(const bf16x8*)(A0 + aoff);
  bf16x8 a2 = *(const bf16x8*)(A1 + aoff);
  bf16x8 a3 = *(const bf16x8*)(A2 + aoff);
  bf16x8 b1 = *(const bf16x8*)(B0 + boff);
  bf16x8 b2 = *(const bf16x8*)(B1 + boff);
  bf16x8 b3 = *(const bf16x8*)(B2 + boff);
  floatx16 c = *acc;
  c = __builtin_amdgcn_mfma_f32_32x32x16_bf16(a1,b1,c,0,0,0);
  c = __builtin_amdgcn_mfma_f32_32x32x16_bf16(a1,b2,c,0,0,0);
  c = __builtin_amdgcn_mfma_f32_32x32x16_bf16(a2,b1,c,0,0,0);
  c = __builtin_amdgcn_mfma_f32_32x32x16_bf16(a1,b3,c,0,0,0);
  c = __builtin_amdgcn_mfma_f32_32x32x16_bf16(a3,b1,c,0,0,0);
  c = __builtin_amdgcn_mfma_f32_32x32x16_bf16(a2,b2,c,0,0,0);
  *acc = c;
}

// ---- generic 64x128 MFMA GEMM core (bf16x6 fp32-faithful) ----
__device__ __forceinline__ void g_gemm(const float* A0, int ldA,
                                       const float* __restrict__ W0, int ldW, int K,
                                       __bf16* pb, floatx16* oA, floatx16* oB){
  __bf16 *As0 = pb, *As1 = pb+2560, *As2 = pb+5120;
  __bf16 *Bs0 = pb+7680, *Bs1 = pb+12800, *Bs2 = pb+17920;
  int tid = threadIdx.x;
  int sar = tid >> 2, sako = (tid & 3)*8;
  int bn = tid & 127, bk = (tid >> 7)*16;
  int wv_ = tid >> 6, L = tid & 63, m = L & 31, half = L >> 5;
  int rA = 32*(wv_ & 1) + m, rB0 = (wv_ >> 1)*32 + m, rB1 = rB0 + 64;
  const float* arow = A0 + (size_t)sar*ldA;
  floatx16 accA, accB;
  #pragma unroll
  for (int i = 0; i < 16; i++){ accA[i] = 0.f; accB[i] = 0.f; }
  float ra[8], wv[16];
  {
    float4 v0 = *(const float4*)(arow + sako);
    float4 v1 = *(const float4*)(arow + sako + 4);
    ra[0]=v0.x; ra[1]=v0.y; ra[2]=v0.z; ra[3]=v0.w; ra[4]=v1.x; ra[5]=v1.y; ra[6]=v1.z; ra[7]=v1.w;
    #pragma unroll
    for (int j = 0; j < 16; j++) wv[j] = W0[(size_t)(bk + j)*ldW + bn];
  }
  for (int k0 = 0; k0 < K; k0 += 32){
    split_store8(ra, As0, As1, As2, SW(sar, sako));
    split_store8(wv,     Bs0, Bs1, Bs2, SW(bn, bk));
    split_store8(wv + 8, Bs0, Bs1, Bs2, SW(bn, bk + 8));
    __syncthreads();
    int k1 = k0 + 32;
    float ra2[8], wv2[16];
    if (k1 < K){
      float4 v0 = *(const float4*)(arow + k1 + sako);
      float4 v1 = *(const float4*)(arow + k1 + sako + 4);
      ra2[0]=v0.x; ra2[1]=v0.y; ra2[2]=v0.z; ra2[3]=v0.w; ra2[4]=v1.x; ra2[5]=v1.y; ra2[6]=v1.z; ra2[7]=v1.w;
      #pragma unroll
      for (int j = 0; j < 16; j++) wv2[j] = W0[(size_t)(k1 + bk + j)*ldW + bn];
    }
    #pragma unroll
    for (int kg = 0; kg < 2; kg++){
      int ko = kg*16 + half*8;
      mfma6(As0,As1,As2, Bs0,Bs1,Bs2, SW(rA,ko), SW(rB0,ko), &accA);
      mfma6(As0,As1,As2, Bs0,Bs1,Bs2, SW(rA,ko), SW(rB1,ko), &accB);
    }
    __syncthreads();
    if (k1 < K){
      #pragma unroll
      for (int j = 0; j < 8; j++) ra[j] = ra2[j];
      #pragma unroll
      for (int j = 0; j < 16; j++) wv[j] = wv2[j];
    }
  }
  *oA = accA; *oB = accB;
}

// ---- generic 64x64-tile MFMA GEMM core ----
__device__ __forceinline__ void g_gemm64(const float* __restrict__ A0, int ldA,
                                         const float* __restrict__ W0, int ldW, int K,
                                         __bf16* pb, floatx16* oC){
  __bf16 *As0 = pb, *As1 = pb+2560, *As2 = pb+5120;
  __bf16 *Bs0 = pb+7680, *Bs1 = pb+10240, *Bs2 = pb+12800;
  int tid = threadIdx.x;
  int sar = tid >> 2, sako = (tid & 3)*8;
  int bn = tid & 63, bk = (tid >> 6)*8;
  int wv_ = tid >> 6, L = tid & 63, m = L & 31, half = L >> 5;
  int rA = 32*(wv_ & 1) + m, rB = 32*(wv_ >> 1) + m;
  const float* arow = A0 + (size_t)sar*ldA;
  floatx16 acc;
  #pragma unroll
  for (int i = 0; i < 16; i++) acc[i] = 0.f;
  float ra[8], wv[8];
  {
    float4 v0 = *(const float4*)(arow + sako);
    float4 v1 = *(const float4*)(arow + sako + 4);
    ra[0]=v0.x; ra[1]=v0.y; ra[2]=v0.z; ra[3]=v0.w; ra[4]=v1.x; ra[5]=v1.y; ra[6]=v1.z; ra[7]=v1.w;
    #pragma unroll
    for (int j = 0; j < 8; j++) wv[j] = W0[(size_t)(bk + j)*ldW + bn];
  }
  for (int k0 = 0; k0 < K; k0 += 32){
    split_store8(ra, As0, As1, As2, SW(sar, sako));
    split_store8(wv, Bs0, Bs1, Bs2, SW(bn, bk));
    __syncthreads();
    int k1 = k0 + 32;
    float ra2[8], wv2[8];
    if (k1 < K){
      float4 v0 = *(const float4*)(arow + k1 + sako);
      float4 v1 = *(const float4*)(arow + k1 + sako + 4);
      ra2[0]=v0.x; ra2[1]=v0.y; ra2[2]=v0.z; ra2[3]=v0.w; ra2[4]=v1.x; ra2[5]=v1.y; ra2[6]=v1.z; ra2[7]=v1.w;
      #pragma unroll
      for (int j = 0; j < 8; j++) wv2[j] = W0[(size_t)(k1 + bk + j)*ldW + bn];
    }
    #pragma unroll
    for (int kg = 0; kg < 2; kg++){
      int ko = kg*16 + half*8;
      mfma6(As0,As1,As2, Bs0,Bs1,Bs2, SW(rA,ko), SW(rB,ko), &acc);
    }
    __syncthreads();
    if (k1 < K){
      #pragma unroll
      for (int j = 0; j < 8; j++){ ra[j] = ra2[j]; wv[j] = wv2[j]; }
    }
  }
  *oC = acc;
}

// ---- 64x64-tile W1 GEMM core (K=384, pre-folded W1f fp32, h=[a,q,a*q] synthesized) ----
__device__ __forceinline__ void g_gemm_h64(const float* __restrict__ arow, const float* __restrict__ qrow,
                                           const float* __restrict__ W1fz, int colbase,
                                           __bf16* pb, floatx16* oC){
  __bf16 *As0 = pb, *As1 = pb+2560, *As2 = pb+5120;
  __bf16 *Bs0 = pb+7680, *Bs1 = pb+10240, *Bs2 = pb+12800;
  int tid = threadIdx.x;
  int sar = tid >> 2, sako = (tid & 3)*8;
  int bn = tid & 63, bk = (tid >> 6)*8;
  int col = colbase + bn;
  int wv_ = tid >> 6, L = tid & 63, m = L & 31, half = L >> 5;
  int rA = 32*(wv_ & 1) + m, rB = 32*(wv_ >> 1) + m;
  auto loadA = [&](int k0, float* r){
    int seg = k0 >> 7, kl = (k0 & 127) + sako;
    if (seg == 0){
      float4 a0 = *(const float4*)(arow + kl), a1 = *(const float4*)(arow + kl + 4);
      r[0]=a0.x; r[1]=a0.y; r[2]=a0.z; r[3]=a0.w; r[4]=a1.x; r[5]=a1.y; r[6]=a1.z; r[7]=a1.w;
    } else if (seg == 1){
      float4 q0 = *(const float4*)(qrow + kl), q1 = *(const float4*)(qrow + kl + 4);
      r[0]=q0.x; r[1]=q0.y; r[2]=q0.z; r[3]=q0.w; r[4]=q1.x; r[5]=q1.y; r[6]=q1.z; r[7]=q1.w;
    } else {
      float4 a0 = *(const float4*)(arow + kl), a1 = *(const float4*)(arow + kl + 4);
      float4 q0 = *(const float4*)(qrow + kl), q1 = *(const float4*)(qrow + kl + 4);
      r[0]=a0.x*q0.x; r[1]=a0.y*q0.y; r[2]=a0.z*q0.z; r[3]=a0.w*q0.w;
      r[4]=a1.x*q1.x; r[5]=a1.y*q1.y; r[6]=a1.z*q1.z; r[7]=a1.w*q1.w;
    }
  };
  auto loadB = [&](int k0, float* r){
    #pragma unroll
    for (int j = 0; j < 8; j++) r[j] = W1fz[(size_t)(k0 + bk + j)*256 + col];
  };
  floatx16 acc;
  #pragma unroll
  for (int i = 0; i < 16; i++) acc[i] = 0.f;
  float ra[8], wv[8];
  loadA(0, ra); loadB(0, wv);
  for (int k0 = 0; k0 < 384; k0 += 32){
    split_store8(ra, As0, As1, As2, SW(sar, sako));
    split_store8(wv, Bs0, Bs1, Bs2, SW(bn, bk));
    __syncthreads();
    int k1 = k0 + 32;
    float ra2[8], wv2[8];
    if (k1 < 384){ loadA(k1, ra2); loadB(k1, wv2); }
    #pragma unroll
    for (int kg = 0; kg < 2; kg++){
      int ko = kg*16 + half*8;
      mfma6(As0,As1,As2, Bs0,Bs1,Bs2, SW(rA,ko), SW(rB,ko), &acc);
    }
    __syncthreads();
    if (k1 < 384){
      #pragma unroll
      for (int j = 0; j < 8; j++){ ra[j] = ra2[j]; wv[j] = wv2[j]; }
    }
  }
  *oC = acc;
}

__device__ __forceinline__ void c_write(floatx16 accA, floatx16 accB, float* C0, int ldC, int act){
  int tid = threadIdx.x, wv_ = tid >> 6, L = tid & 63, m = L & 31, half = L >> 5;
  int rB0 = (wv_ >> 1)*32 + m, rB1 = rB0 + 64;
  int row0 = 32*(wv_ & 1) + 4*half;
  #pragma unroll
  for (int reg = 0; reg < 16; reg++){
    int row = row0 + (reg & 3) + 8*(reg >> 2);
    float va = accA[reg], vb = accB[reg];
    if (act){ va = lrelu(va); vb = lrelu(vb); }
    C0[(size_t)row*ldC + rB0] = va;
    C0[(size_t)row*ldC + rB1] = vb;
  }
}

__device__ __forceinline__ void c_write64(floatx16 acc, float* C0, int ldC, int act){
  int tid = threadIdx.x, wv_ = tid >> 6, L = tid & 63, m = L & 31, half = L >> 5;
  int col = 32*(wv_ >> 1) + m;
  int row0 = 32*(wv_ & 1) + 4*half;
  #pragma unroll
  for (int reg = 0; reg < 16; reg++){
    int row = row0 + (reg & 3) + 8*(reg >> 2);
    float v = acc[reg];
    if (act) v = lrelu(v);
    C0[(size_t)row*ldC + col] = v;
  }
}

// ---- double hop (A^T twice), A in LDS; src either global rows (ld128) or LDS (ldV); dst ld128 ----
__device__ __forceinline__ void hop2_run(const float* A, const float* VfullL, int ldV,
                                         const float* srcG, float* dstG, int dstOff,
                                         float* Vt, float* Tt, int fbeg, int fend){
  int tid = threadIdx.x;
  int tc = (tid & 31)*2, tf = (tid >> 5)*4;
  for (int f0 = fbeg; f0 < fend; f0 += 32){
    if (!VfullL){
      for (int o = tid; o < 2048; o += 256){
        int r = o >> 5, f = o & 31;
        Vt[o] = srcG[r*128 + f0 + f];
      }
      __syncthreads();
    }
    float a00,a01,a02,a03,a10,a11,a12,a13;
    a00=a01=a02=a03=a10=a11=a12=a13=0.f;
    for (int r = 0; r < 64; r++){
      float x0 = A[r*64 + tc], x1 = A[r*64 + tc + 1];
      float4 v4 = VfullL ? *(const float4*)&VfullL[r*ldV + f0 + tf]
                         : *(const float4*)&Vt[r*32 + tf];
      a00 += x0*v4.x; a01 += x0*v4.y; a02 += x0*v4.z; a03 += x0*v4.w;
      a10 += x1*v4.x; a11 += x1*v4.y; a12 += x1*v4.z; a13 += x1*v4.w;
    }
    *(float4*)&Tt[tc*32 + tf]     = make_float4(a00,a01,a02,a03);
    *(float4*)&Tt[(tc+1)*32 + tf] = make_float4(a10,a11,a12,a13);
    __syncthreads();
    a00=a01=a02=a03=a10=a11=a12=a13=0.f;
    for (int r = 0; r < 64; r++){
      float x0 = A[r*64 + tc], x1 = A[r*64 + tc + 1];
      float4 v4 = *(const float4*)&Tt[r*32 + tf];
      a00 += x0*v4.x; a01 += x0*v4.y; a02 += x0*v4.z; a03 += x0*v4.w;
      a10 += x1*v4.x; a11 += x1*v4.y; a12 += x1*v4.z; a13 += x1*v4.w;
    }
    *(float4*)(dstG + tc*128 + dstOff + f0 + tf)     = make_float4(a00,a01,a02,a03);
    *(float4*)(dstG + (tc+1)*128 + dstOff + f0 + tf) = make_float4(a10,a11,a12,a13);
    __syncthreads();
  }
}

// ===== K1: build+hop2 f-split (blk<128) || Wk-f (128..255) || W1 fold (256..319)
//          || A2 zero (320..3023) || xl = x @ linW (3024..3151) || counter zero (3152) =====
__global__ __launch_bounds__(256) void k_p0(const int* __restrict__ ei, const float* __restrict__ ew,
                                            const float* __restrict__ x, const float* __restrict__ Wk,
                                            const float* __restrict__ W1, const float* __restrict__ linW,
                                            float* A_g, float* M_g, float* xq, float* a_buf, float* W1f,
                                            float* xl0, float* xl1, float* outA2, int* icnt){
  __shared__ __align__(16) char POOL[57856];
  float* pf = (float*)POOL;
  __bf16* pb = (__bf16*)POOL;
  int blk = blockIdx.x, tid = threadIdx.x;
  if (blk < 128){
    int b = blk >> 1, fh = blk & 1;
    float* Ws = pf; float* Mc = pf + 4096; float* dv = pf + 8192;
    for (int i = tid; i < 4096; i += 256){ Ws[i] = 0.f; Mc[i] = 0.f; }
    __syncthreads();
    const int* r0 = ei + b*2048;
    const int* c0 = ei + 64*2048 + b*2048;
    const float* w0 = ew + b*2048;
    int base = b*64;
    for (int e = tid; e < 2048; e += 256){
      int r = r0[e] - base, c = c0[e] - base;
      atomicAdd(&Ws[r*64 + c], w0[e]);
      atomicAdd(&Mc[r*64 + c], 1.f);
    }
    if (tid < 64){ atomicAdd(&Ws[tid*65], 1.f); atomicAdd(&Mc[tid*65], 1.f); }
    __syncthreads();
    if (tid < 64){
      float d = 0.f;
      for (int r = 0; r < 64; r++) d += Ws[r*64 + tid];
      dv[tid] = d > 0.f ? rsqrtf(fmaxf(d, 1e-12f)) : 0.f;
    }
    __syncthreads();
    for (int i = tid; i < 4096; i += 256){
      int r = i >> 6, c = i & 63;
      float a = dv[r]*Ws[i]*dv[c];
      Ws[i] = a;
      if (fh == 0){
        A_g[b*4096 + i] = a;
        M_g[b*4096 + i] = Mc[i];
      }
    }
    __syncthreads();
    hop2_run(Ws, nullptr, 0, x + (size_t)b*8192, xq + (size_t)b*8192, 0, pf + 8256, pf + 10304,
             fh*64, fh*64 + 64);
  } else if (blk < 256){
    int idx = blk - 128, z = idx >> 6, b = idx & 63;
    floatx16 cA, cB;
    g_gemm(x + (size_t)b*8192, 128, Wk + (size_t)z*16384, 128, 128, pb, &cA, &cB);
    c_write(cA, cB, a_buf + (size_t)z*524288 + (size_t)b*8192, 128, 0);
  } else if (blk < 320){
    // fold W1 (all 4 heads) -> W1f[head][384][256]
    int idx0 = (blk - 256)*6144;
    for (int i = tid; i < 6144; i += 256){
      int g = idx0 + i;
      int zz = g / 98304;
      int r = g - zz*98304;
      int kr = r >> 8, c = r & 255;
      const float* Wz = W1 + (size_t)zz*131072;
      float v;
      if (kr < 128)       v = Wz[kr*256 + c] + Wz[(kr + 256)*256 + c];
      else if (kr < 256)  v = Wz[kr*256 + c] - Wz[(kr + 128)*256 + c];
      else                v = Wz[(kr + 128)*256 + c];
      W1f[g] = v;
    }
  } else if (blk < 3024){
    // zero-fill full A2 region (44.3 MB); nonzero blocks overwritten later by A2c stage
    float4* p = (float4*)outA2;
    int base = (blk - 320)*1024 + tid;
    #pragma unroll
    for (int i = 0; i < 4; i++) p[base + i*256] = make_float4(0.f,0.f,0.f,0.f);
  } else if (blk < 3152){
    // xl_h = x @ linW_h (2 heads x 64 batches)
    int idx = blk - 3024, z = idx >> 6, b = idx & 63;
    floatx16 cA, cB;
    g_gemm(x + (size_t)b*8192, 128, linW + (size_t)z*16384, 128, 128, pb, &cA, &cB);
    c_write(cA, cB, (z ? xl1 : xl0) + (size_t)b*8192, 128, 0);
  } else {
    // zero the per-batch dependency counters (workspace is re-poisoned each iteration)
    if (tid < 64) icnt[tid*32] = 0;               // cnt_f
    else if (tid < 128) icnt[2048 + (tid - 64)*32] = 0;  // cnt_g
  }
}

// ===== K2: W1 fold GEMM (512 blocks: b,z,nq) — 64x64 tiles =====
__global__ __launch_bounds__(256) void k_h1(const float* __restrict__ a_buf, const float* __restrict__ q0,
                                            const float* __restrict__ tgt, const float* __restrict__ W1fp,
                                            float* h1){
  __shared__ __align__(16) char POOL[30720];
  __bf16* pb = (__bf16*)POOL;
  int blk = blockIdx.x, tid = threadIdx.x;
  int b = blk >> 3, z = (blk >> 2) & 1, nq = blk & 3;
  int sar = tid >> 2;
  const float* arow = a_buf + (size_t)z*524288 + ((size_t)b*64 + sar)*128;
  const float* qrow = z ? (tgt + (size_t)b*128) : (q0 + ((size_t)b*64 + sar)*128);
  floatx16 c;
  g_gemm_h64(arow, qrow, W1fp + (size_t)z*98304, nq*64, pb, &c);
  c_write64(c, h1 + (size_t)z*1048576 + (size_t)b*16384 + nq*64, 256, 1);
}

// ===== w2p body: W2 partial-logit GEMM; lp published via device-scope atomic stores =====
__device__ void w2p_body(int b, int z, int nh, float* pf, __bf16* pb,
                         const float* __restrict__ h1, const float* __restrict__ W2,
                         const float* __restrict__ W3, float* lp){
  float* lgp = pf + 7808;   // beyond g_gemm64's 30720B bf16 pool
  int tid = threadIdx.x;
  floatx16 c;
  g_gemm64(h1 + (size_t)z*1048576 + (size_t)b*16384, 256,
           W2 + (size_t)z*32768 + nh*64, 128, 256, pb, &c);
  int wv_ = tid >> 6, L = tid & 63, m = L & 31, half = L >> 5;
  int col = 32*(wv_ >> 1) + m;
  float w = W3[z*128 + nh*64 + col];
  float v[16];
  #pragma unroll
  for (int reg = 0; reg < 16; reg++) v[reg] = lrelu(c[reg])*w;
  #pragma unroll
  for (int off = 1; off < 32; off <<= 1)
    #pragma unroll
    for (int reg = 0; reg < 16; reg++) v[reg] += __shfl_xor(v[reg], off);
  if (m == 0){
    #pragma unroll
    for (int reg = 0; reg < 16; reg++) lgp[wv_*32 + half*16 + reg] = v[reg];
  }
  __syncthreads();
  if (tid < 64){
    int row = tid, rh = row >> 5, rem = row & 31;
    int hf = (rem >> 2) & 1, rg = (rem & 3) + 4*(rem >> 3);
    float p = lgp[rh*32 + hf*16 + rg] + lgp[(rh + 2)*32 + hf*16 + rg];
    __hip_atomic_store((int*)&lp[(z*2 + nh)*4096 + b*64 + row], __float_as_int(p),
                       __ATOMIC_RELAXED, __HIP_MEMORY_SCOPE_AGENT);
  }
}

__device__ __forceinline__ float lp_ld(const float* lp, int i){
  return __int_as_float(__hip_atomic_load((int*)lp + i, __ATOMIC_RELAXED, __HIP_MEMORY_SCOPE_AGENT));
}

// ===== edgehop job (pool-aliased, R5-verified): edge softmax + S + y=Ew^T xl + x_c + hop2 =====
__device__ void edgehop_job(int b, int fh, float* pf,
                            const float* __restrict__ M_g, const float* lp,
                            const float* __restrict__ x, const float* __restrict__ xl0g,
                            const float* __restrict__ xl1g, const float* __restrict__ A_g,
                            float* S_g, float* xcb, float* xq2){
  float* Mc   = pf;           // 4096; later reused for Ab
  float* xh   = pf + 4096;    // 4096
  float* xl0h = pf + 8192;    // 4096; later reused for Tt
  float* xl1h = pf + 12288;   // 4096
  float* f1s  = pf + 16384;   // 64
  float* f2s  = pf + 16448;   // 64
  int tid = threadIdx.x;
  int foff = fh*64;
  for (int i = tid; i < 4096; i += 256) Mc[i] = M_g[b*4096 + i];
  for (int o = tid*4; o < 4096; o += 1024){
    int r = o >> 6, f = o & 63;
    *(float4*)&xh[o]   = *(const float4*)(x    + (size_t)b*8192 + r*128 + foff + f);
    *(float4*)&xl0h[o] = *(const float4*)(xl0g + (size_t)b*8192 + r*128 + foff + f);
    *(float4*)&xl1h[o] = *(const float4*)(xl1g + (size_t)b*8192 + r*128 + foff + f);
  }
  if (tid < 128){
    int z = tid >> 6, r = tid & 63;
    float d = lp_ld(lp, (z*2)*4096 + b*64 + r) + lp_ld(lp, (z*2 + 1)*4096 + b*64 + r);
    float l = lrelu(d);
    float mx = l;
    #pragma unroll
    for (int off = 32; off; off >>= 1) mx = fmaxf(mx, __shfl_xor(mx, off));
    float e = expf(l - mx);
    float s = e;
    #pragma unroll
    for (int off = 32; off; off >>= 1) s += __shfl_xor(s, off);
    (z ? f2s : f1s)[r] = e/s;
  }
  __syncthreads();
  {
    int c = tid >> 2, sub = tid & 3;
    float m = -1e30f;
    for (int r = sub; r < 64; r += 4)
      if (Mc[r*64 + c] > 0.f) m = fmaxf(m, lrelu(f1s[c] + f2s[r]));
    m = fmaxf(m, __shfl_xor(m, 1));
    m = fmaxf(m, __shfl_xor(m, 2));
    float s = 0.f;
    for (int r = sub; r < 64; r += 4){
      float mc = Mc[r*64 + c];
      if (mc > 0.f) s += mc*expf(lrelu(f1s[c] + f2s[r]) - m);
    }
    s += __shfl_xor(s, 1);
    s += __shfl_xor(s, 2);
    for (int r = sub; r < 64; r += 4){
      float mc = Mc[r*64 + c];
      float v = 0.f;
      if (mc > 0.f) v = mc*expf(lrelu(f1s[c] + f2s[r]) - m)/s;
      Mc[r*64 + c] = v;
    }
  }
  __syncthreads();
  if (fh == 0)
    for (int i = tid; i < 4096; i += 256) S_g[b*4096 + i] = Mc[i];
  {
    int tc = (tid & 15)*4, tf = (tid >> 4)*4;
    float a0[4][4], a1[4][4];
    #pragma unroll
    for (int i = 0; i < 4; i++)
      #pragma unroll
      for (int j = 0; j < 4; j++){ a0[i][j] = 0.f; a1[i][j] = 0.f; }
    for (int r = 0; r < 64; r++){
      float4 e4 = *(const float4*)&Mc[r*64 + tc];
      float4 p0 = *(const float4*)&xl0h[r*64 + tf];
      float4 p1 = *(const float4*)&xl1h[r*64 + tf];
      float e_[4] = {e4.x,e4.y,e4.z,e4.w};
      float p0_[4] = {p0.x,p0.y,p0.z,p0.w};
      float p1_[4] = {p1.x,p1.y,p1.z,p1.w};
      #pragma unroll
      for (int ci = 0; ci < 4; ci++)
        #pragma unroll
        for (int fj = 0; fj < 4; fj++){
          a0[ci][fj] += e_[ci]*p0_[fj];
          a1[ci][fj] += e_[ci]*p1_[fj];
        }
    }
    __syncthreads();
    #pragma unroll
    for (int ci = 0; ci < 4; ci++){
      int c = tc + ci;
      float4 xv = *(const float4*)&xh[c*64 + tf];
      float4 o;
      o.x = 0.5f*(lrelu(xv.x + a0[ci][0]) + lrelu(xv.x + a1[ci][0]));
      o.y = 0.5f*(lrelu(xv.y + a0[ci][1]) + lrelu(xv.y + a1[ci][1]));
      o.z = 0.5f*(lrelu(xv.z + a0[ci][2]) + lrelu(xv.z + a1[ci][2]));
      o.w = 0.5f*(lrelu(xv.w + a0[ci][3]) + lrelu(xv.w + a1[ci][3]));
      *(float4*)&xh[c*64 + tf] = o;
      *(float4*)(xcb + (size_t)b*8192 + c*128 + foff + tf) = o;
    }
  }
  __syncthreads();     // all reads of Mc/xl0h complete -> safe to overwrite
  for (int i = tid*4; i < 4096; i += 1024)
    *(float4*)&Mc[i] = *(const float4*)(A_g + b*4096 + i);   // Ab into Mc slot
  __syncthreads();
  hop2_run(Mc, xh, 64, nullptr, xq2 + (size_t)b*8192, foff, xl0h, xl0h, 0, 64);  // Tt in xl0h slot
}

// ===== A2c job (pool-based, R5-verified): pool + direct A2 block writes =====
__device__ void A2c_job(int b, float* pf, const float* lp, const float* __restrict__ x,
                        const float* __restrict__ A_g, const float* __restrict__ S_g,
                        float* outA2, float* outX, float* outB, float* outP){
  float* At = pf;             // 64*68
  float* Sp = pf + 4352;      // 64*56
  float* Tq = pf + 7936;      // 64*56
  int*   pi = (int*)(pf + 11520);
  float* pv = pf + 11584;
  int tid = threadIdx.x;
  if (tid < 64){
    int lane = tid;
    float f[2];
    #pragma unroll
    for (int z = 0; z < 2; z++){
      float d = lp_ld(lp, (z*2)*4096 + b*64 + lane) + lp_ld(lp, (z*2 + 1)*4096 + b*64 + lane);
      float l = lrelu(d);
      float mx = l;
      #pragma unroll
      for (int off = 32; off; off >>= 1) mx = fmaxf(mx, __shfl_xor(mx, off));
      float e = expf(l - mx);
      float sm = e;
      #pragma unroll
      for (int off = 32; off; off >>= 1) sm += __shfl_xor(sm, off);
      f[z] = e/sm;
    }
    float l = f[0] + f[1];
    float m = l;
    #pragma unroll
    for (int off = 32; off; off >>= 1) m = fmaxf(m, __shfl_xor(m, off));
    float e = expf(l - m);
    float sm = e;
    #pragma unroll
    for (int off = 32; off; off >>= 1) sm += __shfl_xor(sm, off);
    float v = e/sm;
    int idx = lane;
    #pragma unroll
    for (int k = 2; k <= 64; k <<= 1){
      #pragma unroll
      for (int j = k >> 1; j > 0; j >>= 1){
        float ov = __shfl_xor(v, j);
        int   oi = __shfl_xor(idx, j);
        bool ascBlock = (lane & k) == 0;
        bool iAmLow   = (lane & j) == 0;
        bool otherPrec = (ov > v) || (ov == v && oi < idx);
        bool take = (ascBlock == iAmLow) ? otherPrec : !otherPrec;
        if (take){ v = ov; idx = oi; }
      }
    }
    pi[lane] = idx; pv[lane] = v;
    if (lane < KK){
      outB[b*KK + lane] = (float)b;
      outP[b*KK + lane] = (float)(b*64 + idx);
    }
  }
  __syncthreads();
  for (int o = tid*4; o < KK*128; o += 1024){
    int j = o >> 7, f = o & 127;
    float4 xv = *(const float4*)(x + ((size_t)b*64 + pi[j])*128 + f);
    float sv = pv[j];
    *(float4*)(outX + (size_t)b*KK*128 + o) = make_float4(xv.x*sv, xv.y*sv, xv.z*sv, xv.w*sv);
  }
  for (int idx = tid; idx < 4096; idx += 256){
    int i = idx >> 6, k = idx & 63;
    At[k*68 + i] = A_g[b*4096 + idx];
  }
  for (int idx = tid; idx < 4096; idx += 256){
    int k = idx >> 6, t = idx & 63;
    if (t < 56) Sp[k*56 + t] = (t < KK) ? S_g[b*4096 + k*64 + pi[t]] : 0.f;
  }
  __syncthreads();
  if (tid < 224){
    int i0 = (tid/14)*4, t0 = (tid % 14)*4;
    float acc[4][4];
    #pragma unroll
    for (int a = 0; a < 4; a++)
      #pragma unroll
      for (int c = 0; c < 4; c++) acc[a][c] = 0.f;
    for (int k = 0; k < 64; k++){
      float4 a4 = *(const float4*)&At[k*68 + i0];
      float4 s4 = *(const float4*)&Sp[k*56 + t0];
      float a_[4] = {a4.x,a4.y,a4.z,a4.w};
      float s_[4] = {s4.x,s4.y,s4.z,s4.w};
      #pragma unroll
      for (int ii = 0; ii < 4; ii++)
        #pragma unroll
        for (int tt = 0; tt < 4; tt++) acc[ii][tt] += a_[ii]*s_[tt];
    }
    #pragma unroll
    for (int ii = 0; ii < 4; ii++)
      *(float4*)&Tq[(i0+ii)*56 + t0] = make_float4(acc[ii][0],acc[ii][1],acc[ii][2],acc[ii][3]);
  }
  __syncthreads();
  if (tid < 169){
    int a0 = (tid/13)*4, t0 = (tid % 13)*4;
    float acc[4][4];
    #pragma unroll
    for (int a = 0; a < 4; a++)
      #pragma unroll
      for (int c = 0; c < 4; c++) acc[a][c] = 0.f;
    for (int i = 0; i < 64; i++){
      float4 s4 = *(const float4*)&Sp[i*56 + a0];
      float4 t4 = *(const float4*)&Tq[i*56 + t0];
      float s_[4] = {s4.x,s4.y,s4.z,s4.w};
      float t_[4] = {t4.x,t4.y,t4.z,t4.w};
      #pragma unroll
      for (int aa = 0; aa < 4; aa++)
        #pragma unroll
        for (int tt = 0; tt < 4; tt++) acc[aa][tt] += s_[aa]*t_[tt];
    }
    #pragma unroll
    for (int aa = 0; aa < 4; aa++){
      int a = a0 + aa;
      float4 o;
      o.x = (a == t0    ) ? 1.f : acc[aa][0];
      o.y = (a == t0 + 1) ? 1.f : acc[aa][1];
      o.z = (a == t0 + 2) ? 1.f : acc[aa][2];
      o.w = (a == t0 + 3) ? 1.f : acc[aa][3];
      *(float4*)(outA2 + (size_t)(b*KK + a)*NKOUT + b*KK + t0) = o;
    }
  }
}

// ===== K3: w2p pair f (256 blocks) + counter-gated edgehop continuation (last 2 per batch) =====
__global__ __launch_bounds__(256, 2) void k_w2pE(const float* __restrict__ h1, const float* __restrict__ W2,
                                                 const float* __restrict__ W3, float* lp,
                                                 const float* __restrict__ M_g, const float* __restrict__ x,
                                                 const float* __restrict__ xl0, const float* __restrict__ xl1,
                                                 const float* __restrict__ A_g,
                                                 float* S_g, float* xcb, float* xq2, int* cntf){
  __shared__ __align__(16) char POOL[66048];
  __shared__ int s_old;
  float* pf = (float*)POOL;
  __bf16* pb = (__bf16*)POOL;
  int blk = blockIdx.x, tid = threadIdx.x;
  int b = blk >> 2, z = (blk >> 1) & 1, nh = blk & 1;
  w2p_body(b, z, nh, pf, pb, h1, W2, W3, lp);
  if (tid == 0){
    asm volatile("s_waitcnt vmcnt(0)");   // own wave's lp atomic stores complete before counter bump
    s_old = __hip_atomic_fetch_add(&cntf[b*32], 1, __ATOMIC_RELAXED, __HIP_MEMORY_SCOPE_AGENT);
  }
  __syncthreads();
  int old = s_old;
  if (old < 2) return;
  if (old == 2){
    if (tid == 0){
      while (__hip_atomic_load(&cntf[b*32], __ATOMIC_RELAXED, __HIP_MEMORY_SCOPE_AGENT) < 4)
        __builtin_amdgcn_s_sleep(2);
      __hip_atomic_fetch_add(&cntf[b*32], -4, __ATOMIC_RELAXED, __HIP_MEMORY_SCOPE_AGENT);
    }
    __syncthreads();
  }
  edgehop_job(b, old - 2, pf, M_g, lp, x, xl0, xl1, A_g, S_g, xcb, xq2);
}

// ===== K5: Wk pair g (256 blocks: b,z,nh) — 64x64 tiles =====
__global__ __launch_bounds__(256) void k_wkg(const float* __restrict__ xcb, const float* __restrict__ Wkg,
                                             float* a_buf){
  __shared__ __align__(16) char POOL[30720];
  __bf16* pb = (__bf16*)POOL;
  int blk = blockIdx.x;
  int b = blk >> 2, z = (blk >> 1) & 1, nh = blk & 1;
  floatx16 c;
  g_gemm64(xcb + (size_t)b*8192, 128, Wkg + (size_t)z*16384 + nh*64, 128, 128, pb, &c);
  c_write64(c, a_buf + (size_t)z*524288 + (size_t)b*8192 + nh*64, 128, 0);
}

// ===== K6: w2p pair g (256 blocks) + counter-gated A2c continuation (last 1 per batch) =====
__global__ __launch_bounds__(256, 2) void k_w2pA(const float* __restrict__ h1, const float* __restrict__ W2,
                                                 const float* __restrict__ W3, float* lp,
                                                 const float* __restrict__ x, const float* __restrict__ A_g,
                                                 const float* __restrict__ S_g,
                                                 float* outA2, float* outX, float* outB, float* outP,
                                                 int* cntg){
  __shared__ __align__(16) char POOL[66048];
  __shared__ int s_old;
  float* pf = (float*)POOL;
  __bf16* pb = (__bf16*)POOL;
  int blk = blockIdx.x, tid = threadIdx.x;
  int b = blk >> 2, z = (blk >> 1) & 1, nh = blk & 1;
  w2p_body(b, z, nh, pf, pb, h1, W2, W3, lp);
  if (tid == 0){
    asm volatile("s_waitcnt vmcnt(0)");
    s_old = __hip_atomic_fetch_add(&cntg[b*32], 1, __ATOMIC_RELAXED, __HIP_MEMORY_SCOPE_AGENT);
  }
  __syncthreads();
  if (s_old != 3) return;
  if (tid == 0)
    __hip_atomic_fetch_add(&cntg[b*32], -4, __ATOMIC_RELAXED, __HIP_MEMORY_SCOPE_AGENT);
  A2c_job(b, pf, lp, x, A_g, S_g, outA2, outX, outB, outP);
}

extern "C" void kernel_launch(void* const* d_in, const int* in_sizes, int n_in,
                              void* d_out, int out_size, void* d_ws, size_t ws_size,
                              hipStream_t stream){
  const float* x    = (const float*)d_in[0];
  const int*   ei   = (const int*)d_in[1];
  const float* ew   = (const float*)d_in[2];
  const float* tgt  = (const float*)d_in[3];
  const float* Wk   = (const float*)d_in[5];
  const float* W1   = (const float*)d_in[6];
  const float* W2   = (const float*)d_in[7];
  const float* W3   = (const float*)d_in[8];
  const float* linW = (const float*)d_in[9];
  float* out = (float*)d_out;

  float* wf   = (float*)d_ws;
  float* A_g  = wf;
  float* M_g  = wf + 262144;
  float* S_g  = wf + 524288;
  float* xq   = wf + 786432;
  float* xq2  = wf + 1310720;
  float* xl0  = wf + 1835008;
  float* xcb  = wf + 2359296;
  float* a_buf= wf + 2883584;              // 2 x 524288
  float* h1   = wf + 3932160;              // 2 x 1048576 fp32
  float* lp   = wf + 6029312;              // 4 x 4096 partial logits (atomic-published)
  float* W1f  = wf + 6045696;              // 4 x 98304 fp32 folded W1
  float* xl1  = wf + 6438912;              // 524288
  int*   icnt = (int*)(wf + 6963200);      // cnt_f[64] @ stride 32, cnt_g at +2048

  float* outX  = out;
  float* outA2 = out + 425984;
  float* outB  = out + 425984 + 11075584;
  float* outP  = outB + NKOUT;

  // pair f (+ W1 pre-fold + A2 zero-fill + xl precompute + counter zero in spare blocks)
  k_p0<<<dim3(3153), dim3(256), 0, stream>>>(ei, ew, x, Wk, W1, linW, A_g, M_g, xq, a_buf, W1f,
                                             xl0, xl1, outA2, icnt);
  k_h1<<<dim3(512), dim3(256), 0, stream>>>(a_buf, xq, tgt, W1f, h1);
  // fused: w2p pair f -> per-batch counter -> edgehop (last 2 blocks per batch)
  k_w2pE<<<dim3(256), dim3(256), 0, stream>>>(h1, W2, W3, lp, M_g, x, xl0, xl1, A_g,
                                              S_g, xcb, xq2, icnt);
  // pair g
  k_wkg<<<dim3(256), dim3(256), 0, stream>>>(xcb, Wk + 2*16384, a_buf);
  k_h1<<<dim3(512), dim3(256), 0, stream>>>(a_buf, xq2, tgt, W1f + 2*98304, h1);
  // fused: w2p pair g -> per-batch counter -> pool + A2 writes (last block per batch)
  k_w2pA<<<dim3(256), dim3(256), 0, stream>>>(h1, W2 + 2*32768, W3 + 2*128, lp, x, A_g, S_g,
                                              outA2, outX, outB, outP, icnt + 2048);
}